// Round 3
// baseline (6529.137 us; speedup 1.0000x reference)
//
#include <hip/hip_runtime.h>

// GraphEncoder: GINE-style GNN, D=768, 4 layers. fp32 I/O, f16 intermediates +
// f16 MFMA GEMMs, fp32 accumulate/LN/scatter math.
//
// Workspace budget (the round-2 bug): total ws usage now 307 MiB:
//   [WT 12x768x768 f16 | Q (50048x768 f16) | h (Nx768 f16) | e (Ex768 f16)]
// d_out (Nx768 fp32, 153.6MB) doubles as scratch: fp32 agg -> f16 U -> final out.

#define DM 768
#define NLAYERS 4
#define CHUNK 50048  // bond-encoder row chunk (multiple of 128)

typedef _Float16 f16;
typedef __attribute__((ext_vector_type(8))) _Float16 f16x8;
typedef __attribute__((ext_vector_type(4))) _Float16 f16x4;
typedef __attribute__((ext_vector_type(4))) float f32x4;

__device__ __forceinline__ float gelu_f(float x) {
    float x3 = x * x * x;
    return 0.5f * x * (1.0f + tanhf(0.7978845608028654f * (x + 0.044715f * x3)));
}
__device__ __forceinline__ void async16(const void* g, void* l) {
    __builtin_amdgcn_global_load_lds((const __attribute__((address_space(1))) void*)g,
                                     (__attribute__((address_space(3))) void*)l,
                                     16, 0, 0);
}

__device__ __forceinline__ void block_reduce2(float& s1, float& s2, float* sm) {
    #pragma unroll
    for (int off = 32; off > 0; off >>= 1) {
        s1 += __shfl_down(s1, off);
        s2 += __shfl_down(s2, off);
    }
    int lane = threadIdx.x & 63, wid = threadIdx.x >> 6;
    if (lane == 0) { sm[wid * 2] = s1; sm[wid * 2 + 1] = s2; }
    __syncthreads();
    s1 = sm[0] + sm[2] + sm[4] + sm[6];
    s2 = sm[1] + sm[3] + sm[5] + sm[7];
}

// -------- weight transpose + fp32->fp16: Wt[n][k] = W[k][n], 768x768 ----------
__global__ __launch_bounds__(256) void transpose768(
    const float* __restrict__ W, f16* __restrict__ Wt) {
    __shared__ float t[32][33];
    int tx = threadIdx.x, ty = threadIdx.y;
    int c0 = blockIdx.x * 32, r0 = blockIdx.y * 32;
    #pragma unroll
    for (int j = 0; j < 32; j += 8) t[ty + j][tx] = W[(r0 + ty + j) * DM + c0 + tx];
    __syncthreads();
    #pragma unroll
    for (int j = 0; j < 32; j += 8) Wt[(long)(c0 + ty + j) * DM + r0 + tx] = (f16)t[tx][ty + j];
}

// -------- embedding-sum + LayerNorm (encoder front), fp32 in, fp16 out ----------
__global__ __launch_bounds__(256) void embed_ln_kernel(
    const int* __restrict__ ids, int F, int V,
    const float* __restrict__ emb,
    const float* __restrict__ g, const float* __restrict__ b,
    f16* __restrict__ out) {
    int m = blockIdx.x, tid = threadIdx.x;
    float v[3] = {0.f, 0.f, 0.f};
    for (int f = 0; f < F; ++f) {
        int id = ids[(long)m * F + f];
        const float* row = emb + ((long)f * V + id) * DM;
        v[0] += row[tid];
        v[1] += row[tid + 256];
        v[2] += row[tid + 512];
    }
    float s1 = v[0] + v[1] + v[2];
    float s2 = v[0] * v[0] + v[1] * v[1] + v[2] * v[2];
    __shared__ float sm[8];
    block_reduce2(s1, s2, sm);
    float mean = s1 * (1.f / DM);
    float var = s2 * (1.f / DM) - mean * mean;
    float rstd = rsqrtf(var + 1e-5f);
    #pragma unroll
    for (int q = 0; q < 3; ++q) {
        int d = tid + q * 256;
        out[(long)m * DM + d] = (f16)((v[q] - mean) * rstd * g[d] + b[d]);
    }
}

// -------- gelu(U) + h_in -> LayerNorm -> out ----------
template <typename OUT>
__global__ __launch_bounds__(256) void gelu_res_ln_kernel(
    const f16* __restrict__ U, const f16* __restrict__ hin,
    const float* __restrict__ g, const float* __restrict__ b,
    OUT* __restrict__ out) {
    int m = blockIdx.x, tid = threadIdx.x;
    float v[3];
    #pragma unroll
    for (int q = 0; q < 3; ++q) {
        int d = tid + q * 256;
        v[q] = gelu_f((float)U[(long)m * DM + d]) + (float)hin[(long)m * DM + d];
    }
    float s1 = v[0] + v[1] + v[2];
    float s2 = v[0] * v[0] + v[1] * v[1] + v[2] * v[2];
    __shared__ float sm[8];
    block_reduce2(s1, s2, sm);
    float mean = s1 * (1.f / DM);
    float var = s2 * (1.f / DM) - mean * mean;
    float rstd = rsqrtf(var + 1e-5f);
    #pragma unroll
    for (int q = 0; q < 3; ++q) {
        int d = tid + q * 256;
        out[(long)m * DM + d] = (OUT)((v[q] - mean) * rstd * g[d] + b[d]);
    }
}

// -------- edge scatter: agg[dst] += relu(h[src] + e), one wave per edge ----------
__global__ __launch_bounds__(256) void scatter_kernel(
    const int* __restrict__ ei, int E,
    const f16* __restrict__ h, const f16* __restrict__ e,
    float* __restrict__ agg) {
    int wid = blockIdx.x * 4 + (threadIdx.x >> 6);
    int lane = threadIdx.x & 63;
    if (wid >= E) return;
    int src = ei[wid];
    int dst = ei[E + wid];
    const f16* hr = h + (long)src * DM;
    const f16* er = e + (long)wid * DM;
    float* ar = agg + (long)dst * DM;
    #pragma unroll
    for (int it = 0; it < 3; ++it) {
        int base = lane * 4 + it * 256;
        f16x4 hv = *(const f16x4*)&hr[base];
        f16x4 ev = *(const f16x4*)&er[base];
        float m0 = (float)hv.x + (float)ev.x;
        float m1 = (float)hv.y + (float)ev.y;
        float m2 = (float)hv.z + (float)ev.z;
        float m3 = (float)hv.w + (float)ev.w;
        if (m0 > 0.f) atomicAdd(&ar[base + 0], m0);
        if (m1 > 0.f) atomicAdd(&ar[base + 1], m1);
        if (m2 > 0.f) atomicAdd(&ar[base + 2], m2);
        if (m3 > 0.f) atomicAdd(&ar[base + 3], m3);
    }
}

// -------- z = f16(h + agg) ----------
__global__ __launch_bounds__(256) void add_hagg_kernel(
    const f16* __restrict__ h, const float* __restrict__ agg,
    f16* __restrict__ z, long n4) {
    long i = (long)blockIdx.x * blockDim.x + threadIdx.x;
    if (i >= n4) return;
    f16x4 hv = ((const f16x4*)h)[i];
    float4 av = ((const float4*)agg)[i];
    f16x4 zv;
    zv.x = (f16)((float)hv.x + av.x);
    zv.y = (f16)((float)hv.y + av.y);
    zv.z = (f16)((float)hv.z + av.z);
    zv.w = (f16)((float)hv.w + av.w);
    ((f16x4*)z)[i] = zv;
}

// -------- GEMM: C[M,768] = act(A[M,768] @ W + bias), Bt[n][k] = W[k][n] ----------
#define ACT_NONE 0
#define ACT_RELU 1
#define ACT_GELU 2

template <int ACT>
__global__ __launch_bounds__(256, 2) void gemm768(
    const f16* __restrict__ A,      // [M,768] f16; rows may overread <=127 past M (mapped)
    const f16* __restrict__ Bt,     // [768,768] f16, Bt[n][k] = W[k][n]
    const float* __restrict__ bias, // [768] fp32
    f16* __restrict__ C,            // [M,768] f16
    int M) {
    __shared__ f16 As[128 * 32];
    __shared__ f16 Bs[128 * 32];
    int tid = threadIdx.x;
    int lane = tid & 63;
    int wid = tid >> 6;
    int wm = wid >> 1, wn = wid & 1;
    long rowBase = (long)blockIdx.x * 128;
    const f16* Ab = A + rowBase * DM;
    const f16* Bb = Bt + (long)blockIdx.y * 128 * DM;

    f32x4 acc[4][4];
    #pragma unroll
    for (int i = 0; i < 4; ++i)
        #pragma unroll
        for (int j = 0; j < 4; ++j) acc[i][j] = (f32x4){0.f, 0.f, 0.f, 0.f};

    int sr = wid * 32;
    int lr = lane >> 2;
    int lc = (lane & 3) * 8;
    int fm = lane & 15;
    int fk = (lane >> 4) * 8;

    for (int kt = 0; kt < DM / 32; ++kt) {
        int k0 = kt * 32;
        const f16* g0 = Ab + (long)(sr + lr) * DM + k0 + lc;
        async16(g0, &As[sr * 32]);
        async16(g0 + 16 * DM, &As[(sr + 16) * 32]);
        const f16* h0 = Bb + (long)(sr + lr) * DM + k0 + lc;
        async16(h0, &Bs[sr * 32]);
        async16(h0 + 16 * DM, &Bs[(sr + 16) * 32]);
        __syncthreads();

        f16x8 af[4], bfr[4];
        #pragma unroll
        for (int i = 0; i < 4; ++i)
            af[i] = *(const f16x8*)&As[(wm * 64 + i * 16 + fm) * 32 + fk];
        #pragma unroll
        for (int j = 0; j < 4; ++j)
            bfr[j] = *(const f16x8*)&Bs[(wn * 64 + j * 16 + fm) * 32 + fk];
        #pragma unroll
        for (int i = 0; i < 4; ++i)
            #pragma unroll
            for (int j = 0; j < 4; ++j)
                acc[i][j] = __builtin_amdgcn_mfma_f32_16x16x32_f16(af[i], bfr[j], acc[i][j], 0, 0, 0);
        __syncthreads();
    }

    int row0 = (int)rowBase + wm * 64;
    int col0 = blockIdx.y * 128 + wn * 64;
    #pragma unroll
    for (int j = 0; j < 4; ++j) {
        int c = col0 + j * 16 + (lane & 15);
        float bv = bias[c];
        #pragma unroll
        for (int i = 0; i < 4; ++i) {
            #pragma unroll
            for (int r = 0; r < 4; ++r) {
                int row = row0 + i * 16 + (lane >> 4) * 4 + r;
                if (row < M) {
                    float v = acc[i][j][r] + bv;
                    if (ACT == ACT_RELU) v = v > 0.f ? v : 0.f;
                    if (ACT == ACT_GELU) v = gelu_f(v);
                    C[(long)row * DM + c] = (f16)v;
                }
            }
        }
    }
}

extern "C" void kernel_launch(void* const* d_in, const int* in_sizes, int n_in,
                              void* d_out, int out_size, void* d_ws, size_t ws_size,
                              hipStream_t stream) {
    const int* x  = (const int*)d_in[0];
    const int* ea = (const int*)d_in[1];
    const int* ei = (const int*)d_in[2];
    const float* atom_emb  = (const float*)d_in[3];
    const float* atom_ln_g = (const float*)d_in[4];
    const float* atom_ln_b = (const float*)d_in[5];
    const float* atom_w1   = (const float*)d_in[6];
    const float* atom_b1   = (const float*)d_in[7];
    const float* atom_w2   = (const float*)d_in[8];
    const float* atom_b2   = (const float*)d_in[9];
    const float* bond_emb  = (const float*)d_in[10];
    const float* bond_ln_g = (const float*)d_in[11];
    const float* bond_ln_b = (const float*)d_in[12];
    const float* bond_w1   = (const float*)d_in[13];
    const float* bond_b1   = (const float*)d_in[14];
    const float* bond_w2   = (const float*)d_in[15];
    const float* bond_b2   = (const float*)d_in[16];
    const float* conv_w1   = (const float*)d_in[17];
    const float* conv_b1   = (const float*)d_in[18];
    const float* conv_w2   = (const float*)d_in[19];
    const float* conv_b2   = (const float*)d_in[20];
    const float* ln_g      = (const float*)d_in[21];
    const float* ln_b      = (const float*)d_in[22];

    const int N = in_sizes[0] / 9;
    const int E = in_sizes[1] / 3;
    const long SZ = (long)DM * DM;

    // ---- workspace: WT | Q | h | e  (~307 MiB total) ----
    char* ws = (char*)d_ws;
    size_t off = 0;
    f16* WT = (f16*)(ws + off); off += ((size_t)12 * SZ * 2 + 4095) & ~(size_t)4095;
    f16* Q  = (f16*)(ws + off); off += ((size_t)CHUNK * DM * 2 + 4095) & ~(size_t)4095;
    f16* h  = (f16*)(ws + off); off += ((size_t)N * DM * 2 + 4095) & ~(size_t)4095;
    f16* e  = (f16*)(ws + off); off += ((size_t)E * DM * 2 + 4095) & ~(size_t)4095;
    // d_out region (N*DM fp32): agg (fp32) / U (f16, <=CHUNK rows) / final output
    float* agg = (float*)d_out;
    f16*   U   = (f16*)d_out;

    dim3 tb(32, 8), tg(24, 24);
    transpose768<<<tg, tb, 0, stream>>>(atom_w1, WT + 0 * SZ);
    transpose768<<<tg, tb, 0, stream>>>(atom_w2, WT + 1 * SZ);
    transpose768<<<tg, tb, 0, stream>>>(bond_w1, WT + 2 * SZ);
    transpose768<<<tg, tb, 0, stream>>>(bond_w2, WT + 3 * SZ);
    for (int l = 0; l < NLAYERS; ++l) {
        transpose768<<<tg, tb, 0, stream>>>(conv_w1 + l * SZ, WT + (4 + l) * SZ);
        transpose768<<<tg, tb, 0, stream>>>(conv_w2 + l * SZ, WT + (8 + l) * SZ);
    }

    dim3 gn((N + 127) / 128, DM / 128);

    // AtomEncoder: h = gelu(LN(sum emb) @ w1 + b1) @ w2 + b2   (Q -> U(d_out) -> h)
    embed_ln_kernel<<<N, 256, 0, stream>>>(x, 9, 128, atom_emb, atom_ln_g, atom_ln_b, Q);
    gemm768<ACT_GELU><<<gn, 256, 0, stream>>>(Q, WT + 0 * SZ, atom_b1, U, N);
    gemm768<ACT_NONE><<<gn, 256, 0, stream>>>(U, WT + 1 * SZ, atom_b2, h, N);

    // BondEncoder in CHUNK-row chunks: Q -> U(d_out) -> e[c0..]
    for (int c0 = 0; c0 < E; c0 += CHUNK) {
        int rows = E - c0 < CHUNK ? E - c0 : CHUNK;
        dim3 gc((rows + 127) / 128, DM / 128);
        embed_ln_kernel<<<rows, 256, 0, stream>>>(ea + (long)c0 * 3, 3, 8,
                                                  bond_emb, bond_ln_g, bond_ln_b, Q);
        gemm768<ACT_GELU><<<gc, 256, 0, stream>>>(Q, WT + 2 * SZ, bond_b1, U, rows);
        gemm768<ACT_NONE><<<gc, 256, 0, stream>>>(U, WT + 3 * SZ, bond_b2, e + (long)c0 * DM, rows);
    }

    long n4 = (long)N * DM / 4;
    for (int l = 0; l < NLAYERS; ++l) {
        hipMemsetAsync(agg, 0, (size_t)N * DM * 4, stream);
        scatter_kernel<<<(E + 3) / 4, 256, 0, stream>>>(ei, E, h, e, agg);
        add_hagg_kernel<<<(int)((n4 + 255) / 256), 256, 0, stream>>>(h, agg, Q, n4);  // z -> Q
        gemm768<ACT_RELU><<<gn, 256, 0, stream>>>(Q, WT + (4 + l) * SZ, conv_b1 + l * DM, U, N);  // U -> d_out
        gemm768<ACT_NONE><<<gn, 256, 0, stream>>>(U, WT + (8 + l) * SZ, conv_b2 + l * DM, Q, N);  // V -> Q
        if (l == NLAYERS - 1) {
            gelu_res_ln_kernel<float><<<N, 256, 0, stream>>>(Q, h, ln_g + l * DM, ln_b + l * DM, (float*)d_out);
        } else {
            gelu_res_ln_kernel<f16><<<N, 256, 0, stream>>>(Q, h, ln_g + l * DM, ln_b + l * DM, h);
        }
    }
}